// Round 1
// 14862.221 us; speedup vs baseline: 1.1427x; 1.1427x over previous
//
#include <hip/hip_runtime.h>

#define BN 8
#define CN 128
#define HN 128
#define WN 256
#define PLANE (HN*WN)        // 32768
#define BSTRIDE (CN*PLANE)   // 4194304
#define WELEM (CN*CN*9)      // 147456 floats per direction

// Pack w[co][ci][k] -> Wq[g][c4][k][i][j], g=co/4, j=co%4, c4=ci/4, i=ci%4.
// A block owns co-quads g = cot*4..cot*4+3 -> one contiguous 72 KB slab that
// is copied to LDS once per pass (weights are step-invariant).
__global__ void pack_w_kernel(const float* __restrict__ w0, const float* __restrict__ w1,
                              const float* __restrict__ w2, const float* __restrict__ w3,
                              float* __restrict__ Wq) {
    int t = blockIdx.x * 256 + threadIdx.x;
    if (t >= 4 * WELEM) return;
    int p  = t / WELEM;
    int r  = t % WELEM;
    int co = r / (CN * 9);
    int q  = r % (CN * 9);
    int ci = q / 9;
    int k  = q % 9;
    const float* w = (p == 0) ? w0 : (p == 1) ? w1 : (p == 2) ? w2 : w3;
    int g = co >> 2, j = co & 3, c4 = ci >> 2, i = ci & 3;
    Wq[p * WELEM + ((g * 32 + c4) * 9 + k) * 16 + i * 4 + j] = w[r];
}

// One directional pass. Recurrence state flows through FR (l-major lines,
// FR[parity][b][l][ci]) with fine-grained agent-scope atomics; per-(step,
// tile,batch,co-tile) flags; NO cache-wide fences anywhere.
// v2: weights live in LDS (uniform ds_read_b128 broadcast) instead of the
// SGPR-starved SMEM path; staging halo trimmed 8 -> 4 (LW 80 -> 72).
template<int SSTRIDE, int LSTRIDE, int SLEN, int LLEN, int NLT, bool REV>
__global__ void __launch_bounds__(256)
pass_kernel(float* __restrict__ T, const float* __restrict__ Wq,
            float* __restrict__ FR, unsigned int* __restrict__ FLG) {
    constexpr int NCOT  = 8;     // co-tiles (16 co per block)
    constexpr int LW    = 72;    // 64-wide tile + 4 halo each side (K=9 -> ±4)
    constexpr int PITCH = 132;   // 128 ci + 4 pad (breaks bank collision)
    constexpr int WQUAD = 32 * 9 * 16;          // 4608 floats per co-quad
    __shared__ float sP[LW * PITCH];            // 38,016 B
    __shared__ float sW[4 * WQUAD];             // 73,728 B  (total 111,744 B)

    const int blk = blockIdx.x;
    const int b   = blk / (NCOT * NLT);
    const int rem = blk % (NCOT * NLT);
    const int cot = rem / NLT;
    const int lt  = rem % NLT;
    const int lane = threadIdx.x & 63;
    const int wv   = __builtin_amdgcn_readfirstlane((int)threadIdx.x >> 6);
    const int co0  = cot * 16 + wv * 4;
    const int l_base = lt * 64;
    const int l      = l_base + lane;
    const size_t b_off = (size_t)b * BSTRIDE;
    const int lo = (lt > 0) ? lt - 1 : 0;
    const int hi = (lt < NLT - 1) ? lt + 1 : NLT - 1;
    const int nd = (hi - lo + 1) * NCOT;

    // ---- one-time: block's 4 co-quads of weights -> LDS (coalesced float4)
    {
        const float4* wsrc = (const float4*)(Wq + (size_t)cot * 4 * WQUAD);
        float4* wdst = (float4*)sW;
        for (int r = threadIdx.x; r < 4 * WQUAD / 4; r += 256)
            wdst[r] = wsrc[r];
    }
    __syncthreads();
    const float* wbase = sW + wv * WQUAD;       // wave-uniform LDS base

    for (int t = 1; t < SLEN; ++t) {
        const int s  = REV ? (SLEN - 1 - t) : t;
        const int sp = REV ? (s + 1) : (s - 1);
        const size_t oidx = b_off + (size_t)co0 * PLANE
                          + (size_t)s * SSTRIDE + (size_t)l * LSTRIDE;

        // x prefetch (our own co's only -> no cross-block hazard); overlaps poll.
        float xv0 = T[oidx];
        float xv1 = T[oidx + PLANE];
        float xv2 = T[oidx + 2 * (size_t)PLANE];
        float xv3 = T[oidx + 3 * (size_t)PLANE];

        // ---- wait for producers of step t-1 (tiles lo..hi, all co-tiles)
        if (t > 1 && (int)threadIdx.x < nd) {
            int qt = lo + ((int)threadIdx.x >> 3);
            int cq = (int)threadIdx.x & 7;
            const unsigned int* f =
                &FLG[(((t - 1) * NLT + qt) * BN + b) * NCOT + cq];
            while (__hip_atomic_load(f, __ATOMIC_RELAXED,
                                     __HIP_MEMORY_SCOPE_AGENT) == 0u)
                __builtin_amdgcn_s_sleep(1);
        }
        __syncthreads();

        // ---- stage previous line into LDS (l-major, ci-interleaved)
        if (t == 1) {
            const float* Tp = T + b_off + (size_t)sp * SSTRIDE;
            for (int r = threadIdx.x; r < LW * CN; r += 256) {
                int rl = r >> 7;          // / CN
                int ci = r & (CN - 1);
                int gl = l_base - 4 + rl;
                float v = 0.f;
                if (gl >= 0 && gl < LLEN)
                    v = Tp[(size_t)ci * PLANE + (size_t)gl * LSTRIDE];
                sP[rl * PITCH + ci] = v;
            }
        } else {
            const float* src = FR + (size_t)(((t - 1) & 1) * BN + b) * (CN * LLEN);
            for (int r = threadIdx.x; r < LW * (CN / 4); r += 256) {
                int rl = r >> 5;          // / 32
                int c4 = r & 31;
                int gl = l_base - 4 + rl;
                unsigned long long u0 = 0ull, u1 = 0ull;
                if (gl >= 0 && gl < LLEN) {
                    const unsigned long long* p =
                        (const unsigned long long*)(src + (size_t)gl * CN + c4 * 4);
                    u0 = __hip_atomic_load(p,     __ATOMIC_RELAXED, __HIP_MEMORY_SCOPE_AGENT);
                    u1 = __hip_atomic_load(p + 1, __ATOMIC_RELAXED, __HIP_MEMORY_SCOPE_AGENT);
                }
                float4 v;
                *(unsigned long long*)&v.x = u0;
                *(unsigned long long*)&v.z = u1;
                *(float4*)&sP[rl * PITCH + c4 * 4] = v;
            }
        }
        __syncthreads();

        // ---- conv: 4 co per thread, 4 ci per ds_read_b128; weights via
        //      wave-uniform ds_read_b128 broadcast (in-order lgkmcnt, no SMEM)
        float a0 = 0.f, a1 = 0.f, a2 = 0.f, a3 = 0.f;
        for (int c4 = 0; c4 < 32; ++c4) {
            const float* wr  = wbase + c4 * 144;
            const float* spb = &sP[lane * PITCH + c4 * 4];   // rows lane..lane+8 = l-4..l+4
            float4 tap[9];
#pragma unroll
            for (int k = 0; k < 9; ++k)
                tap[k] = *(const float4*)(spb + k * PITCH);
#pragma unroll
            for (int k = 0; k < 9; ++k) {
                const float4 w0 = *(const float4*)(wr + k * 16);
                const float4 w1 = *(const float4*)(wr + k * 16 + 4);
                const float4 w2 = *(const float4*)(wr + k * 16 + 8);
                const float4 w3 = *(const float4*)(wr + k * 16 + 12);
                a0 = fmaf(w0.x, tap[k].x, a0); a1 = fmaf(w0.y, tap[k].x, a1);
                a2 = fmaf(w0.z, tap[k].x, a2); a3 = fmaf(w0.w, tap[k].x, a3);
                a0 = fmaf(w1.x, tap[k].y, a0); a1 = fmaf(w1.y, tap[k].y, a1);
                a2 = fmaf(w1.z, tap[k].y, a2); a3 = fmaf(w1.w, tap[k].y, a3);
                a0 = fmaf(w2.x, tap[k].z, a0); a1 = fmaf(w2.y, tap[k].z, a1);
                a2 = fmaf(w2.z, tap[k].z, a2); a3 = fmaf(w2.w, tap[k].z, a3);
                a0 = fmaf(w3.x, tap[k].w, a0); a1 = fmaf(w3.y, tap[k].w, a1);
                a2 = fmaf(w3.z, tap[k].w, a2); a3 = fmaf(w3.w, tap[k].w, a3);
            }
        }
        const float o0 = xv0 + (a0 > 0.f ? a0 : 0.f);
        const float o1 = xv1 + (a1 > 0.f ? a1 : 0.f);
        const float o2 = xv2 + (a2 > 0.f ? a2 : 0.f);
        const float o3 = xv3 + (a3 > 0.f ? a3 : 0.f);

        // ---- publish new line to FR (write-through atomics), then flag
        {
            float* dst = FR + ((size_t)((t & 1) * BN + b) * LLEN + l) * CN + co0;
            float2 p0 = make_float2(o0, o1), p1 = make_float2(o2, o3);
            __hip_atomic_store((unsigned long long*)dst,
                               *(unsigned long long*)&p0,
                               __ATOMIC_RELAXED, __HIP_MEMORY_SCOPE_AGENT);
            __hip_atomic_store((unsigned long long*)dst + 1,
                               *(unsigned long long*)&p1,
                               __ATOMIC_RELAXED, __HIP_MEMORY_SCOPE_AGENT);
        }
        __builtin_amdgcn_s_waitcnt(0);   // drain own write-through stores
        __syncthreads();                 // now ALL block stores are at coherence point
        if (threadIdx.x == 0) {
            __hip_atomic_store(&FLG[((t * NLT + lt) * BN + b) * NCOT + cot], 1u,
                               __ATOMIC_RELAXED, __HIP_MEMORY_SCOPE_AGENT);
        }

        // ---- background output write (off critical path; L2 absorbs strides)
        T[oidx]                       = o0;
        T[oidx + PLANE]               = o1;
        T[oidx + 2 * (size_t)PLANE]   = o2;
        T[oidx + 3 * (size_t)PLANE]   = o3;
    }
}

extern "C" void kernel_launch(void* const* d_in, const int* in_sizes, int n_in,
                              void* d_out, int out_size, void* d_ws, size_t ws_size,
                              hipStream_t stream) {
    const float* x  = (const float*)d_in[0];
    const float* wd = (const float*)d_in[1];
    const float* wu = (const float*)d_in[2];
    const float* wr = (const float*)d_in[3];
    const float* wl = (const float*)d_in[4];
    float* T = (float*)d_out;

    float* Wq = (float*)d_ws;                        // 2.36 MB
    float* FR = Wq + 4 * WELEM;                      // 2 MB
    unsigned int* FLG = (unsigned int*)(FR + 2 * BN * CN * WN);  // 1 MB

    hipMemcpyAsync(T, x, (size_t)BN * CN * HN * WN * sizeof(float),
                   hipMemcpyDeviceToDevice, stream);
    pack_w_kernel<<<(4 * WELEM + 255) / 256, 256, 0, stream>>>(wd, wu, wr, wl, Wq);
    hipMemsetAsync(FLG, 0, 4 * 65536 * sizeof(unsigned int), stream);

    // H passes: scan h (SSTRIDE=WN), line = w (contiguous), 256 blocks.
    {
        float* W = Wq; unsigned int* F = FLG;
        void* args[] = { &T, &W, &FR, &F };
        hipLaunchCooperativeKernel((const void*)pass_kernel<WN, 1, HN, WN, 4, false>,
                                   dim3(BN * 8 * 4), dim3(256), args, 0, stream);
    }
    {
        float* W = Wq + WELEM; unsigned int* F = FLG + 65536;
        void* args[] = { &T, &W, &FR, &F };
        hipLaunchCooperativeKernel((const void*)pass_kernel<WN, 1, HN, WN, 4, true>,
                                   dim3(BN * 8 * 4), dim3(256), args, 0, stream);
    }
    // W passes: scan w (SSTRIDE=1), line = h (stride WN), 128 blocks.
    {
        float* W = Wq + 2 * WELEM; unsigned int* F = FLG + 2 * 65536;
        void* args[] = { &T, &W, &FR, &F };
        hipLaunchCooperativeKernel((const void*)pass_kernel<1, WN, WN, HN, 2, false>,
                                   dim3(BN * 8 * 2), dim3(256), args, 0, stream);
    }
    {
        float* W = Wq + 3 * WELEM; unsigned int* F = FLG + 3 * 65536;
        void* args[] = { &T, &W, &FR, &F };
        hipLaunchCooperativeKernel((const void*)pass_kernel<1, WN, WN, HN, 2, true>,
                                   dim3(BN * 8 * 2), dim3(256), args, 0, stream);
    }
}

// Round 2
// 6316.598 us; speedup vs baseline: 2.6886x; 2.3529x over previous
//
#include <hip/hip_runtime.h>

#define BN 8
#define CN 128
#define HN 128
#define WN 256
#define PLANE (HN*WN)        // 32768
#define BSTRIDE (CN*PLANE)   // 4194304
#define WELEM (CN*CN*9)      // 147456 floats per direction

typedef __attribute__((ext_vector_type(8))) short bf16x8;
typedef __attribute__((ext_vector_type(4))) float f32x4;

// fp32 -> bf16 (RNE) and back, for the hi/lo split-bf16 emulation.
__device__ __host__ inline unsigned short f2bf(float f) {
    union { float f; unsigned u; } v; v.f = f;
    unsigned u = v.u;
    unsigned r = (u + 0x7fffu + ((u >> 16) & 1u)) >> 16;
    return (unsigned short)r;
}
__device__ __host__ inline float bf2f(unsigned short h) {
    union { unsigned u; float f; } v; v.u = ((unsigned)h) << 16;
    return v.f;
}

// Weight slab per (dir p, co-tile cot): A[16 co][K=1152], K = k*128 + ci,
// split hi/lo bf16, stored as the EXACT LDS image (XOR-swizzled rows):
//   byte(co_r, K) = co_r*2304 + K*2, swizzled ^= (co_r&7)<<4
//   hi at slab+0 (36864 B), lo at slab+36864. Slab = 73728 B.
// Pass kernel block-copies its slab linearly into LDS (m173 pattern: source
// is pre-swizzled, LDS copy stays linear).
__global__ void pack_w_kernel(const float* __restrict__ w0, const float* __restrict__ w1,
                              const float* __restrict__ w2, const float* __restrict__ w3,
                              unsigned short* __restrict__ Wa) {
    int t = blockIdx.x * 256 + threadIdx.x;
    if (t >= 4 * WELEM) return;
    int p  = t / WELEM;
    int r  = t % WELEM;
    int co = r / (CN * 9);
    int q  = r % (CN * 9);
    int ci = q / 9;
    int k  = q % 9;
    const float* w = (p == 0) ? w0 : (p == 1) ? w1 : (p == 2) ? w2 : w3;
    float val = w[r];
    unsigned short hi = f2bf(val);
    unsigned short lo = f2bf(val - bf2f(hi));
    int cot = co >> 4, cr = co & 15;
    int K = k * 128 + ci;
    int byte = cr * 2304 + K * 2;
    byte ^= (cr & 7) << 4;
    char* slab = (char*)Wa + ((size_t)p * 8 + cot) * 73728;
    *(unsigned short*)(slab + byte) = hi;
    *(unsigned short*)(slab + 36864 + byte) = lo;
}

// One directional pass. Recurrence state flows through FR (l-major lines,
// FR[parity][b][l][ci], fp32) with agent-scope atomics; per-(step,tile,batch,
// co-tile) flags; NO cache-wide fences.
// v3: conv computed on matrix cores. Per block: D[16co][64l] = A[16co][1152] x
// B[1152][64l] via mfma_f32_16x16x32_bf16, fp32 emulated as hi+lo bf16
// (3 MFMAs: hi*hi + hi*lo + lo*hi; error ~2^-17, fp32-equivalent here).
// Weights resident in LDS for the whole pass; staged line stored as
// swizzled hi/lo bf16.
template<int SSTRIDE, int LSTRIDE, int SLEN, int LLEN, int NLT, bool REV>
__global__ void __launch_bounds__(256)
pass_kernel(float* __restrict__ T, const unsigned short* __restrict__ Wa,
            float* __restrict__ FR, unsigned int* __restrict__ FLG) {
    constexpr int NCOT = 8;      // co-tiles (16 co per block)
    constexpr int LW   = 72;     // 64-wide tile + 4 halo each side (K=9 -> +-4)
    __shared__ __align__(16) char sA[73728];   // A hi (36864) + lo (36864)
    __shared__ __align__(16) char sB[36864];   // B hi (18432) + lo (18432)

    const int blk = blockIdx.x;
    const int b   = blk / (NCOT * NLT);
    const int rem = blk % (NCOT * NLT);
    const int cot = rem / NLT;
    const int lt  = rem % NLT;
    const int lane = threadIdx.x & 63;
    const int wv   = __builtin_amdgcn_readfirstlane((int)threadIdx.x >> 6);
    const int nloc = lane & 15;        // MFMA N-column within wave tile
    const int half = lane >> 4;        // 0..3 (K-quarter / C-row group)
    const int co0  = cot * 16 + half * 4;          // this lane's 4 output co
    const int l_base = lt * 64;
    const int l      = l_base + wv * 16 + nloc;    // this lane's output l
    const size_t b_off = (size_t)b * BSTRIDE;
    const int lo_t = (lt > 0) ? lt - 1 : 0;
    const int hi_t = (lt < NLT - 1) ? lt + 1 : NLT - 1;
    const int nd = (hi_t - lo_t + 1) * NCOT;

    // ---- one-time: this block's weight slab -> LDS (pre-swizzled image)
    {
        const float4* wsrc = (const float4*)((const char*)Wa + (size_t)cot * 73728);
        float4* wdst = (float4*)sA;
        for (int r = threadIdx.x; r < 73728 / 16; r += 256)
            wdst[r] = wsrc[r];
    }
    __syncthreads();

    char* sBh = sB;
    char* sBl = sB + 18432;
    const char* sAh = sA;
    const char* sAl = sA + 36864;
    const int asw   = (nloc & 7) << 4;
    const int abase = nloc * 2304 + half * 16;

    for (int t = 1; t < SLEN; ++t) {
        const int s  = REV ? (SLEN - 1 - t) : t;
        const int sp = REV ? (s + 1) : (s - 1);
        const size_t oidx = b_off + (size_t)co0 * PLANE
                          + (size_t)s * SSTRIDE + (size_t)l * LSTRIDE;

        // x prefetch (own co's only -> no cross-block hazard); overlaps poll.
        float xv0 = T[oidx];
        float xv1 = T[oidx + PLANE];
        float xv2 = T[oidx + 2 * (size_t)PLANE];
        float xv3 = T[oidx + 3 * (size_t)PLANE];

        // ---- wait for producers of step t-1 (tiles lo..hi, all co-tiles)
        if (t > 1 && (int)threadIdx.x < nd) {
            int qt = lo_t + ((int)threadIdx.x >> 3);
            int cq = (int)threadIdx.x & 7;
            const unsigned int* f =
                &FLG[(((t - 1) * NLT + qt) * BN + b) * NCOT + cq];
            while (__hip_atomic_load(f, __ATOMIC_RELAXED,
                                     __HIP_MEMORY_SCOPE_AGENT) == 0u)
                __builtin_amdgcn_s_sleep(1);
        }
        __syncthreads();

        // ---- stage previous line into LDS as swizzled hi/lo bf16
        if (t == 1) {
            const float* Tp = T + b_off + (size_t)sp * SSTRIDE;
            for (int r = threadIdx.x; r < LW * CN; r += 256) {
                int rl = r >> 7;          // / CN
                int ci = r & (CN - 1);
                int gl = l_base - 4 + rl;
                float v = 0.f;
                if (gl >= 0 && gl < LLEN)
                    v = Tp[(size_t)ci * PLANE + (size_t)gl * LSTRIDE];
                unsigned short h = f2bf(v);
                unsigned short w16 = f2bf(v - bf2f(h));
                int byte = (rl * 256 + ci * 2) ^ ((rl & 7) << 4);
                *(unsigned short*)(sBh + byte) = h;
                *(unsigned short*)(sBl + byte) = w16;
            }
        } else {
            const float* src = FR + (size_t)(((t - 1) & 1) * BN + b) * (CN * LLEN);
            for (int r = threadIdx.x; r < LW * (CN / 4); r += 256) {
                int rl = r >> 5;          // / 32
                int c4 = r & 31;
                int gl = l_base - 4 + rl;
                unsigned long long u0 = 0ull, u1 = 0ull;
                if (gl >= 0 && gl < LLEN) {
                    const unsigned long long* p =
                        (const unsigned long long*)(src + (size_t)gl * CN + c4 * 4);
                    u0 = __hip_atomic_load(p,     __ATOMIC_RELAXED, __HIP_MEMORY_SCOPE_AGENT);
                    u1 = __hip_atomic_load(p + 1, __ATOMIC_RELAXED, __HIP_MEMORY_SCOPE_AGENT);
                }
                float4 v;
                *(unsigned long long*)&v.x = u0;
                *(unsigned long long*)&v.z = u1;
                ushort4 h4, l4;
                h4.x = f2bf(v.x); l4.x = f2bf(v.x - bf2f(h4.x));
                h4.y = f2bf(v.y); l4.y = f2bf(v.y - bf2f(h4.y));
                h4.z = f2bf(v.z); l4.z = f2bf(v.z - bf2f(h4.z));
                h4.w = f2bf(v.w); l4.w = f2bf(v.w - bf2f(h4.w));
                int byte = (rl * 256 + c4 * 8) ^ ((rl & 7) << 4);
                *(ushort4*)(sBh + byte) = h4;
                *(ushort4*)(sBl + byte) = l4;
            }
        }
        __syncthreads();

        // ---- conv on matrix cores: 36 K-steps x 3 MFMA (hi*hi, hi*lo, lo*hi)
        f32x4 acc = {0.f, 0.f, 0.f, 0.f};
#pragma unroll
        for (int kk = 0; kk < 36; ++kk) {
            int aoff = (abase + kk * 64) ^ asw;
            int rl   = wv * 16 + nloc + (kk >> 2);
            int boff = (rl * 256 + (kk & 3) * 64 + half * 16) ^ ((rl & 7) << 4);
            bf16x8 ah = *(const bf16x8*)(sAh + aoff);
            bf16x8 al = *(const bf16x8*)(sAl + aoff);
            bf16x8 bh = *(const bf16x8*)(sBh + boff);
            bf16x8 bl = *(const bf16x8*)(sBl + boff);
            acc = __builtin_amdgcn_mfma_f32_16x16x32_bf16(ah, bh, acc, 0, 0, 0);
            acc = __builtin_amdgcn_mfma_f32_16x16x32_bf16(ah, bl, acc, 0, 0, 0);
            acc = __builtin_amdgcn_mfma_f32_16x16x32_bf16(al, bh, acc, 0, 0, 0);
        }
        const float o0 = xv0 + (acc[0] > 0.f ? acc[0] : 0.f);
        const float o1 = xv1 + (acc[1] > 0.f ? acc[1] : 0.f);
        const float o2 = xv2 + (acc[2] > 0.f ? acc[2] : 0.f);
        const float o3 = xv3 + (acc[3] > 0.f ? acc[3] : 0.f);

        // ---- publish new line to FR (write-through atomics), then flag
        {
            float* dst = FR + ((size_t)((t & 1) * BN + b) * LLEN + l) * CN + co0;
            float2 p0 = make_float2(o0, o1), p1 = make_float2(o2, o3);
            __hip_atomic_store((unsigned long long*)dst,
                               *(unsigned long long*)&p0,
                               __ATOMIC_RELAXED, __HIP_MEMORY_SCOPE_AGENT);
            __hip_atomic_store((unsigned long long*)dst + 1,
                               *(unsigned long long*)&p1,
                               __ATOMIC_RELAXED, __HIP_MEMORY_SCOPE_AGENT);
        }
        __builtin_amdgcn_s_waitcnt(0);   // drain own write-through stores
        __syncthreads();                 // all block stores at coherence point
        if (threadIdx.x == 0) {
            __hip_atomic_store(&FLG[((t * NLT + lt) * BN + b) * NCOT + cot], 1u,
                               __ATOMIC_RELAXED, __HIP_MEMORY_SCOPE_AGENT);
        }

        // ---- background output write (off critical path; L2 absorbs strides)
        T[oidx]                       = o0;
        T[oidx + PLANE]               = o1;
        T[oidx + 2 * (size_t)PLANE]   = o2;
        T[oidx + 3 * (size_t)PLANE]   = o3;
    }
}

extern "C" void kernel_launch(void* const* d_in, const int* in_sizes, int n_in,
                              void* d_out, int out_size, void* d_ws, size_t ws_size,
                              hipStream_t stream) {
    const float* x  = (const float*)d_in[0];
    const float* wd = (const float*)d_in[1];
    const float* wu = (const float*)d_in[2];
    const float* wr = (const float*)d_in[3];
    const float* wl = (const float*)d_in[4];
    float* T = (float*)d_out;

    unsigned short* Wa = (unsigned short*)d_ws;                 // 2.36 MB
    float* FR = (float*)((char*)d_ws + 4 * 8 * 73728);          // 2 MB
    unsigned int* FLG = (unsigned int*)(FR + 2 * BN * CN * WN); // 1 MB
    const size_t WDIR = 8 * 73728 / 2;   // ushorts per direction

    hipMemcpyAsync(T, x, (size_t)BN * CN * HN * WN * sizeof(float),
                   hipMemcpyDeviceToDevice, stream);
    pack_w_kernel<<<(4 * WELEM + 255) / 256, 256, 0, stream>>>(wd, wu, wr, wl, Wa);
    hipMemsetAsync(FLG, 0, 4 * 65536 * sizeof(unsigned int), stream);

    // H passes: scan h (SSTRIDE=WN), line = w (contiguous), 256 blocks.
    {
        const unsigned short* W = Wa; unsigned int* F = FLG;
        void* args[] = { &T, &W, &FR, &F };
        hipLaunchCooperativeKernel((const void*)pass_kernel<WN, 1, HN, WN, 4, false>,
                                   dim3(BN * 8 * 4), dim3(256), args, 0, stream);
    }
    {
        const unsigned short* W = Wa + WDIR; unsigned int* F = FLG + 65536;
        void* args[] = { &T, &W, &FR, &F };
        hipLaunchCooperativeKernel((const void*)pass_kernel<WN, 1, HN, WN, 4, true>,
                                   dim3(BN * 8 * 4), dim3(256), args, 0, stream);
    }
    // W passes: scan w (SSTRIDE=1), line = h (stride WN), 128 blocks.
    {
        const unsigned short* W = Wa + 2 * WDIR; unsigned int* F = FLG + 2 * 65536;
        void* args[] = { &T, &W, &FR, &F };
        hipLaunchCooperativeKernel((const void*)pass_kernel<1, WN, WN, HN, 2, false>,
                                   dim3(BN * 8 * 2), dim3(256), args, 0, stream);
    }
    {
        const unsigned short* W = Wa + 3 * WDIR; unsigned int* F = FLG + 3 * 65536;
        void* args[] = { &T, &W, &FR, &F };
        hipLaunchCooperativeKernel((const void*)pass_kernel<1, WN, WN, HN, 2, true>,
                                   dim3(BN * 8 * 2), dim3(256), args, 0, stream);
    }
}